// Round 1
// 742.394 us; speedup vs baseline: 1.0174x; 1.0174x over previous
//
#include <hip/hip_runtime.h>
#include <hip/hip_fp16.h>

#define N_TOK 65536
#define K_EMB 8192
#define D_DIM 256
#define LIST_CAP 12288
#define CAND_CAP 16384

typedef unsigned short u16;
typedef unsigned int u32;
typedef unsigned long long u64;
typedef _Float16 f16x8 __attribute__((ext_vector_type(8)));
typedef float f32x16 __attribute__((ext_vector_type(16)));

__device__ __forceinline__ u16 f2h(float f) {   // f32 -> f16 bits, RNE
  union { _Float16 h; u16 u; } c; c.h = (_Float16)f; return c.u;
}
__device__ __forceinline__ f16x8 as_f16x8(uint4 v) {
  union { uint4 u; f16x8 h; } c; c.u = v; return c.h;
}
__device__ __forceinline__ void gld_lds16(const u16* g, u16* l) {
  __builtin_amdgcn_global_load_lds((const __attribute__((address_space(1))) void*)g,
                                   (__attribute__((address_space(3))) void*)l,
                                   16, 0, 0);
}

// ---------------------------------------------------------------- prep
// ehh[k][d]=f16(emb*2^19); e2f[k]=fl32(sum e^2, f64); e2h[k]=f16(-e2*2^24).
// Zeroes both atomic counters (fresh every call -> graph-replay safe).
__global__ void vq_prep(const float* __restrict__ emb, u16* __restrict__ ehh,
                        float* __restrict__ e2f, u16* __restrict__ e2h,
                        int* __restrict__ count, int* __restrict__ candcount) {
  if (blockIdx.x == 0 && threadIdx.x == 0) { *count = 0; *candcount = 0; }
  const int w = threadIdx.x >> 6, lane = threadIdx.x & 63;
  const int k = blockIdx.x * 4 + w;
  const float4 v = ((const float4*)(emb + (size_t)k * D_DIM))[lane];
  uint2 p;
  p.x = (u32)f2h(v.x * 524288.0f) | ((u32)f2h(v.y * 524288.0f) << 16);
  p.y = (u32)f2h(v.z * 524288.0f) | ((u32)f2h(v.w * 524288.0f) << 16);
  ((uint2*)(ehh + (size_t)k * D_DIM))[lane] = p;
  double s = (double)v.x * v.x + (double)v.y * v.y +
             (double)v.z * v.z + (double)v.w * v.w;
  #pragma unroll
  for (int off = 32; off > 0; off >>= 1) s += __shfl_down(s, off);
  if (lane == 0) { e2f[k] = (float)s; e2h[k] = f2h(-(float)s * 16777216.0f); }
}

// ---------------------------------------------------------------- z2
// z2f[n] = fl32(sum z^2 in f64) — ref-semantics row norm (±1ulp of np's,
// argmin-invariant by grid shift-invariance).
__global__ void vq_z2(const float* __restrict__ zg, float* __restrict__ z2f) {
  const int w = threadIdx.x >> 6, lane = threadIdx.x & 63;
  const int n = blockIdx.x * 4 + w;
  const float4 v = ((const float4*)(zg + (size_t)n * D_DIM))[lane];
  double s = (double)v.x * v.x + (double)v.y * v.y +
             (double)v.z * v.z + (double)v.w * v.w;
  #pragma unroll
  for (int off = 32; off > 0; off >>= 1) s += __shfl_down(s, off);
  if (lane == 0) z2f[n] = (float)s;
}

// ---------------------------------------------------------------- phase 1
// f16 MFMA GEMM, acc = 2^24*(z2 - dist_approx); per-row signed-packed top-2.
// 128 rows/block, grid 512 -> 2 blocks/CU (LDS 64 KB, VGPR<=128): one block's
// VALU top-2 scan + barrier drain overlaps the other's MFMA.
__launch_bounds__(512, 4)
__global__ void vq_phase1(const float* __restrict__ zg, const u16* __restrict__ ehh,
                          const u16* __restrict__ e2h, const float* __restrict__ z2f,
                          int* __restrict__ idx1_ws, int* __restrict__ thrbuf,
                          u64* __restrict__ refbuf, int* __restrict__ list,
                          int* __restrict__ count) {
  __shared__ u16 lds[2][16384];   // 2 x 32 KB frag-major emb-f16 tiles

  const int tid  = threadIdx.x;
  const int w    = tid >> 6;
  const int lane = tid & 63;
  const int q    = w & 1;          // k-substrip (32 k rows)
  const int g    = w >> 1;         // n-group (32 rows)
  const int col  = lane & 31;
  const int h    = lane >> 5;
  const int n0   = blockIdx.x * 128 + g * 32;

  // z fragments: f32 load once, f16(z*64), resident in 64 VGPRs
  uint4 zres[16];
  {
    const float4* zp = (const float4*)(zg + (size_t)(n0 + col) * D_DIM);
    #pragma unroll
    for (int c = 0; c < 16; ++c) {
      float4 a = zp[c * 4 + h * 2];
      float4 b = zp[c * 4 + h * 2 + 1];
      uint4 u;
      u.x = (u32)f2h(a.x * 64.0f) | ((u32)f2h(a.y * 64.0f) << 16);
      u.y = (u32)f2h(a.z * 64.0f) | ((u32)f2h(a.w * 64.0f) << 16);
      u.z = (u32)f2h(b.x * 64.0f) | ((u32)f2h(b.y * 64.0f) << 16);
      u.w = (u32)f2h(b.z * 64.0f) | ((u32)f2h(b.w * 64.0f) << 16);
      zres[c] = u;
    }
  }
  uint4 bone = {0, 0, 0, 0};
  if (h == 0) bone.x = 0x3C00u;          // f16 1.0 at kk=0 (e2-fold B-fragment)

  int m1 = (int)0x80000000, m2 = (int)0x80000000;

  // stage tile 0: 32 chunks (1 KB each), 4 per wave
  #pragma unroll
  for (int i = 0; i < 4; ++i) {
    int pp = w * 4 + i, qs = pp >> 4, cs = pp & 15;
    gld_lds16(ehh + (size_t)(qs * 32 + col) * D_DIM + cs * 16 + h * 8,
              &lds[0][qs * 8192 + cs * 512]);
  }

  for (int t = 0; t < 128; ++t) {
    const int b = t & 1;
    __syncthreads();                 // tile t staged; tile t-1 readers done
    if (t + 1 < 128) {
      const int nb = b ^ 1, kb2 = (t + 1) * 64;
      #pragma unroll
      for (int i = 0; i < 4; ++i) {
        int pp = w * 4 + i, qs = pp >> 4, cs = pp & 15;
        gld_lds16(ehh + (size_t)(kb2 + qs * 32 + col) * D_DIM + cs * 16 + h * 8,
                  &lds[nb][qs * 8192 + cs * 512]);
      }
    }
    const int kb = t * 64 + q * 32;
    uint4 ea = {0, 0, 0, 0};
    if (h == 0) ea.x = (u32)e2h[kb + col];   // f16(-e2*2^24) at kk=0

    const u16* lb = &lds[b][q * 8192];
    f32x16 acc = {};
    #pragma unroll
    for (int c = 0; c < 16; ++c) {
      f16x8 a = as_f16x8(*(const uint4*)(lb + c * 512 + lane * 8));
      acc = __builtin_amdgcn_mfma_f32_32x32x16_f16(a, as_f16x8(zres[c]), acc, 0, 0, 0);
    }
    acc = __builtin_amdgcn_mfma_f32_32x32x16_f16(as_f16x8(ea), as_f16x8(bone), acc, 0, 0, 0);

    const int base_inv = 4095 - t * 32 - q * 16;
    #pragma unroll
    for (int r = 0; r < 16; ++r) {
      // low 12 bits disjoint from acc<<12 -> '+' == '|'; enables lshl_add + inline -r
      int key = ((int)acc[r] << 12) + (base_inv - r);
      m2 = max(m2, min(m1, key));
      m1 = max(m1, key);
    }
  }

  // decode own k, then merge half-wave k-partitions (lanes l and l^32 share n)
  int k1;
  {
    int x = 4095 - (m1 & 4095);
    int kt = x >> 5, kq = (x >> 4) & 1, kr = x & 15;
    k1 = kt * 64 + kq * 32 + (kr & 3) + 8 * (kr >> 2) + 4 * h;
    int o1 = __shfl_xor(m1, 32), o2 = __shfl_xor(m2, 32);
    int ok1 = __shfl_xor(k1, 32);
    bool take = (o1 > m1) || (o1 == m1 && ok1 < k1);
    int loser = take ? m1 : o1;
    if (take) { m1 = o1; k1 = ok1; }
    m2 = max(m2, max(o2, loser));
  }

  __syncthreads();                // tile reads done; alias lds[0] for reduction
  int* rm1 = (int*)&lds[0][0];    // [2][128] each
  int* rk1 = (int*)&lds[0][1024];
  int* rm2 = (int*)&lds[0][2048];
  if (lane < 32) {
    int nl = q * 128 + g * 32 + col;
    rm1[nl] = m1; rk1[nl] = k1; rm2[nl] = m2;
  }
  __syncthreads();
  if (tid < 128) {
    int a1 = rm1[tid], a2 = rm2[tid], ak = rk1[tid];
    int c1 = rm1[128 + tid], c2 = rm2[128 + tid], ck = rk1[128 + tid];
    bool take = (c1 > a1) || (c1 == a1 && ck < ak);
    int M1 = take ? c1 : a1;
    int K1 = take ? ck : ak;
    int M2 = max(max(a2, c2), take ? a1 : c1);
    int n = blockIdx.x * 128 + tid;
    int M1a = M1 >> 12, M2a = M2 >> 12;
    // per-row f32 bin width of the ref's distance (~z2) in 2^-24 units:
    // bin = 2^(exp-126); +0.01 bump covers just-below-power-of-2 rows.
    int e = (int)((__float_as_uint(z2f[n] + 0.01f) >> 23) & 255);
    e = min(max(e, 127), 140);
    int bin = 1 << (e - 126);
    int p = 0;
    if ((M1a - M2a) < (bin * 2 + 128)) {
      int pos = atomicAdd(count, 1);
      if (pos < LIST_CAP) {
        list[pos] = n;
        thrbuf[pos] = M1a - (bin + 256);    // candidate-pass threshold
        refbuf[pos] = 0xFFFFFFFFFFFFFFFFULL;
        p = pos + 1;
      }
    }
    idx1_ws[n] = K1 | (p << 13);
  }
}

// ---------------------------------------------------------------- cand
// Re-run the bit-identical quantized GEMM on flagged (compacted) rows only;
// push every k whose acc >= per-row threshold. Double-buffered LDS (2x64 KB)
// so next-tile staging overlaps MFMA instead of a full serial drain per tile.
__launch_bounds__(512, 2)
__global__ void vq_cand(const float* __restrict__ zg, const u16* __restrict__ ehh,
                        const u16* __restrict__ e2h, const int* __restrict__ count,
                        const int* __restrict__ list, const int* __restrict__ thrbuf,
                        u32* __restrict__ candbuf, int* __restrict__ candcount) {
  __shared__ u16 lds[2][32768];       // 2 x 64 KB: 128 k x 256 d f16, frag-major
  int cnt = *count; if (cnt > LIST_CAP) cnt = LIST_CAP;
  const int tile = blockIdx.x;
  if (tile * 64 >= cnt) return;
  const int tid = threadIdx.x, w = tid >> 6, lane = tid & 63;
  const int q = w & 3, g = w >> 2;     // q: k-substrip(0..3), g: row-group(0..1)
  const int col = lane & 31, h = lane >> 5;
  const int ct = tile * 64 + g * 32 + col;       // compact-row index
  const bool valid = ct < cnt;
  const int n_tok = valid ? (list[ct] & (N_TOK - 1)) : 0;
  const int thr = valid ? thrbuf[ct] : 0x7FFFFFFF;

  uint4 zres[16];
  {
    const float4* zp = (const float4*)(zg + (size_t)n_tok * D_DIM);
    #pragma unroll
    for (int c = 0; c < 16; ++c) {
      float4 a = zp[c * 4 + h * 2];
      float4 b2 = zp[c * 4 + h * 2 + 1];
      uint4 u;
      u.x = (u32)f2h(a.x * 64.0f) | ((u32)f2h(a.y * 64.0f) << 16);
      u.y = (u32)f2h(a.z * 64.0f) | ((u32)f2h(a.w * 64.0f) << 16);
      u.z = (u32)f2h(b2.x * 64.0f) | ((u32)f2h(b2.y * 64.0f) << 16);
      u.w = (u32)f2h(b2.z * 64.0f) | ((u32)f2h(b2.w * 64.0f) << 16);
      zres[c] = u;
    }
  }
  uint4 bone = {0, 0, 0, 0};
  if (h == 0) bone.x = 0x3C00u;

  // stage tile 0: 64 chunks (1 KB each), 8 per wave
  #pragma unroll
  for (int i = 0; i < 8; ++i) {
    int p2 = w * 8 + i, qs = p2 >> 4, cs = p2 & 15;
    gld_lds16(ehh + (size_t)(qs * 32 + col) * D_DIM + cs * 16 + h * 8,
              &lds[0][qs * 8192 + cs * 512]);
  }

  for (int tK = 0; tK < 64; ++tK) {
    const int b = tK & 1;
    __syncthreads();                  // tile tK staged; tile tK-1 readers done
    if (tK + 1 < 64) {
      const int nb = b ^ 1, kb2 = (tK + 1) * 128;
      #pragma unroll
      for (int i = 0; i < 8; ++i) {
        int p2 = w * 8 + i, qs = p2 >> 4, cs = p2 & 15;
        gld_lds16(ehh + (size_t)(kb2 + qs * 32 + col) * D_DIM + cs * 16 + h * 8,
                  &lds[nb][qs * 8192 + cs * 512]);
      }
    }
    const int kb = tK * 128 + q * 32;
    uint4 ea = {0, 0, 0, 0};
    if (h == 0) ea.x = (u32)e2h[kb + col];
    const u16* lb = &lds[b][q * 8192];
    f32x16 acc = {};
    #pragma unroll
    for (int c = 0; c < 16; ++c) {    // same order as phase1 -> bit-identical
      f16x8 a = as_f16x8(*(const uint4*)(lb + c * 512 + lane * 8));
      acc = __builtin_amdgcn_mfma_f32_32x32x16_f16(a, as_f16x8(zres[c]), acc, 0, 0, 0);
    }
    acc = __builtin_amdgcn_mfma_f32_32x32x16_f16(as_f16x8(ea), as_f16x8(bone), acc, 0, 0, 0);
    #pragma unroll
    for (int r = 0; r < 16; ++r) {
      if ((int)acc[r] >= thr) {
        int kg = kb + (r & 3) + 8 * (r >> 2) + 4 * h;
        int pos = atomicAdd(candcount, 1);
        if (pos < CAND_CAP) candbuf[pos] = ((u32)ct << 13) | (u32)kg;
      }
    }
  }
}

// ---------------------------------------------------------------- refine2
// Per candidate: val = fl32(fl32(z2+e2) - 2*fl32(dot)) exactly as np-f32 does;
// key = (val_bits<<13)|k, atomicMin -> min val, tie -> lowest k (first-occurrence).
__global__ void vq_refine2(const float* __restrict__ zg, const float* __restrict__ emb,
                           const float* __restrict__ z2f, const float* __restrict__ e2f,
                           const int* __restrict__ list, const int* __restrict__ candcount,
                           const u32* __restrict__ candbuf, u64* __restrict__ refbuf) {
  const int w = threadIdx.x >> 6, lane = threadIdx.x & 63;
  int ccnt = *candcount; if (ccnt > CAND_CAP) ccnt = CAND_CAP;
  for (int i = blockIdx.x * 4 + w; i < ccnt; i += gridDim.x * 4) {
    const u32 rec = candbuf[i];
    const int p = (int)(rec >> 13), k = (int)(rec & 8191u);
    const int n = list[p] & (N_TOK - 1);
    float4 zv = ((const float4*)(zg + (size_t)n * D_DIM))[lane];
    float4 ev = ((const float4*)(emb + (size_t)k * D_DIM))[lane];
    double s = (double)zv.x * ev.x + (double)zv.y * ev.y +
               (double)zv.z * ev.z + (double)zv.w * ev.w;
    #pragma unroll
    for (int off = 32; off > 0; off >>= 1) s += __shfl_down(s, off);
    if (lane == 0) {
      float S = z2f[n] + e2f[k];           // fl32(z2+e2)
      float val = S - 2.0f * (float)s;     // fl32(S - 2*fl32(dot))
      u64 key = ((u64)__float_as_uint(val) << 13) | (u64)k;
      atomicMin((unsigned long long*)(refbuf + p), (unsigned long long)key);
    }
  }
}

// ---------------------------------------------------------------- gather
// f32 outputs: quantized = straight_through = emb[idx]; indices as f32.
__global__ void vq_gather(const float* __restrict__ emb, const int* __restrict__ idx1_ws,
                          const u64* __restrict__ refbuf, float* __restrict__ out) {
  const int w = threadIdx.x >> 6, lane = threadIdx.x & 63;
  const int n = blockIdx.x * 4 + w;
  const int enc = idx1_ws[n];
  int idx = enc & 8191;
  const int p = enc >> 13;
  if (p > 0) {
    u64 rb = refbuf[p - 1];
    if (rb != 0xFFFFFFFFFFFFFFFFULL) idx = (int)(rb & 8191ULL);
  }
  float4 v = ((const float4*)(emb + (size_t)idx * D_DIM))[lane];
  float4* o = (float4*)out;
  o[(size_t)n * 64 + lane] = v;
  o[(size_t)4194304 + (size_t)n * 64 + lane] = v;         // + N*D (float4 units)
  if (lane == 0) out[(size_t)33554432 + n] = (float)idx;  // + 2*N*D (float units)
}

extern "C" void kernel_launch(void* const* d_in, const int* in_sizes, int n_in,
                              void* d_out, int out_size, void* d_ws, size_t ws_size,
                              hipStream_t stream) {
  const float* z   = (const float*)d_in[0];
  const float* emb = (const float*)d_in[1];
  char* ws = (char*)d_ws;
  // Layout (bytes), total 5,029,896 — within the 5.38 MB envelope round 2 ran in.
  u16*   ehh       = (u16*)(ws);                  // [0        .. 4194304)
  float* e2f       = (float*)(ws + 4194304);      // [4194304  .. 4227072)
  u16*   e2h       = (u16*)(ws + 4227072);        // [4227072  .. 4243456)
  float* z2f       = (float*)(ws + 4243456);      // [4243456  .. 4505600)
  int*   idx1_ws   = (int*)(ws + 4505600);        // [4505600  .. 4767744)
  u64*   refbuf    = (u64*)(ws + 4767744);        // [4767744  .. 4866048)  12288*8
  int*   list      = (int*)(ws + 4866048);        // [4866048  .. 4915200)  12288*4
  int*   thrbuf    = (int*)(ws + 4915200);        // [4915200  .. 4964352)  12288*4
  u32*   candbuf   = (u32*)(ws + 4964352);        // [4964352  .. 5029888)  16384*4
  int*   count     = (int*)(ws + 5029888);        // [5029888  .. 5029892)
  int*   candcount = (int*)(ws + 5029892);        // [5029892  .. 5029896)

  vq_prep   <<<K_EMB / 4, 256, 0, stream>>>(emb, ehh, e2f, e2h, count, candcount);
  vq_z2     <<<N_TOK / 4, 256, 0, stream>>>(z, z2f);
  vq_phase1 <<<N_TOK / 128, 512, 0, stream>>>(z, ehh, e2h, z2f, idx1_ws, thrbuf,
                                              refbuf, list, count);
  vq_cand   <<<256, 512, 0, stream>>>(z, ehh, e2h, count, list, thrbuf,
                                      candbuf, candcount);
  vq_refine2<<<256, 256, 0, stream>>>(z, emb, z2f, e2f, list, candcount,
                                      candbuf, refbuf);
  vq_gather <<<N_TOK / 4, 256, 0, stream>>>(emb, idx1_ws, refbuf, (float*)d_out);
}